// Round 2
// baseline (429.166 us; speedup 1.0000x reference)
//
#include <hip/hip_runtime.h>
#include <hip/hip_bf16.h>
#include <type_traits>

typedef __bf16 bf16;
typedef __bf16 bf16x8 __attribute__((ext_vector_type(8)));
typedef float floatx4 __attribute__((ext_vector_type(4)));

#define LDT 40   // 32 k + 8 pad (row stride 80 B = 16B-aligned)
#define ALD 72   // 64 + 8 pad (row stride 144 B = 16B-aligned)

// ---------------- weight transpose + fp32->bf16: in [R,C] fp32 -> out [C,R] bf16 ----
__global__ __launch_bounds__(256) void wtrans_kernel(const float* __restrict__ in,
                                                     bf16* __restrict__ out,
                                                     int R, int C) {
  __shared__ bf16 t[32][33];
  int tx = threadIdx.x, ty = threadIdx.y;  // (32, 8)
  int c = blockIdx.x * 32 + tx;
#pragma unroll
  for (int i = 0; i < 4; i++) {
    int r = blockIdx.y * 32 + ty + i * 8;
    t[ty + i * 8][tx] = (bf16)in[(long)r * C + c];
  }
  __syncthreads();
  int oc = blockIdx.y * 32 + tx;
#pragma unroll
  for (int i = 0; i < 4; i++) {
    int orr = blockIdx.x * 32 + ty + i * 8;
    out[(long)orr * R + oc] = t[tx][ty + i * 8];
  }
}

// ---------------- C[M,N] = A[M,K] @ Bt[N,K]^T + bias ----------------
// AT = float (converted to bf16 at staging) or bf16. OutT = bf16 or float.
template <typename AT, typename OutT>
__global__ __launch_bounds__(256) void gemm_bias_kernel(const AT* __restrict__ A,
                                                        const bf16* __restrict__ Bt,
                                                        const float* __restrict__ bias,
                                                        OutT* __restrict__ Cc,
                                                        int M, int N, int K) {
  __shared__ alignas(16) bf16 As[64 * LDT];
  __shared__ alignas(16) bf16 Bs[64 * LDT];
  const int tid = threadIdx.x;
  const int wave = tid >> 6, lane = tid & 63;
  const int l16 = lane & 15, l4 = lane >> 4;
  const int n0 = blockIdx.x * 64, m0 = blockIdx.y * 64;
  const int srow = tid >> 2, sch = (tid & 3) * 8;
  const AT* Ap = A + (long)(m0 + srow) * K + sch;
  const bf16* Bp = Bt + (long)(n0 + srow) * K + sch;

  floatx4 acc[4];
#pragma unroll
  for (int i = 0; i < 4; i++) acc[i] = (floatx4){0.f, 0.f, 0.f, 0.f};

  for (int k0 = 0; k0 < K; k0 += 32) {
    bf16x8 av;
    if constexpr (std::is_same_v<AT, float>) {
      float4 f0 = *(const float4*)(Ap + k0);
      float4 f1 = *(const float4*)(Ap + k0 + 4);
      av[0] = (bf16)f0.x; av[1] = (bf16)f0.y; av[2] = (bf16)f0.z; av[3] = (bf16)f0.w;
      av[4] = (bf16)f1.x; av[5] = (bf16)f1.y; av[6] = (bf16)f1.z; av[7] = (bf16)f1.w;
    } else {
      av = *(const bf16x8*)(Ap + k0);
    }
    bf16x8 bv = *(const bf16x8*)(Bp + k0);
    __syncthreads();
    *(bf16x8*)&As[srow * LDT + sch] = av;
    *(bf16x8*)&Bs[srow * LDT + sch] = bv;
    __syncthreads();
    bf16x8 af = *(const bf16x8*)&As[(wave * 16 + l16) * LDT + l4 * 8];
#pragma unroll
    for (int nt = 0; nt < 4; nt++) {
      bf16x8 bfr = *(const bf16x8*)&Bs[(nt * 16 + l16) * LDT + l4 * 8];
      acc[nt] = __builtin_amdgcn_mfma_f32_16x16x32_bf16(af, bfr, acc[nt], 0, 0, 0);
    }
  }
#pragma unroll
  for (int nt = 0; nt < 4; nt++) {
    int col = n0 + nt * 16 + l16;
    float bval = bias[col];
#pragma unroll
    for (int r = 0; r < 4; r++) {
      int row = m0 + wave * 16 + l4 * 4 + r;
      float v = acc[nt][r] + bval;
      if constexpr (std::is_same_v<OutT, float>) Cc[(long)row * N + col] = v;
      else                                       Cc[(long)row * N + col] = (bf16)v;
    }
  }
}

// ---------------- fused self(causal)+cross flash attention (all bf16 buffers) ------
// grid (T/64, H, B), 256 threads. Q/K/V buffers are [B*L, C] with head offset h*64.
__global__ __launch_bounds__(256) void attn_kernel(const bf16* __restrict__ Qb,
                                                   const bf16* __restrict__ Kb,
                                                   const bf16* __restrict__ Vb,
                                                   const bf16* __restrict__ Qcb,
                                                   const bf16* __restrict__ Kcb,
                                                   const bf16* __restrict__ Vcb,
                                                   bf16* __restrict__ Y) {
  __shared__ alignas(16) bf16 Qs[64 * ALD];
  __shared__ alignas(16) bf16 Ks[64 * ALD];
  __shared__ alignas(16) bf16 Vts[64 * ALD];  // transposed: [d][key]
  __shared__ alignas(16) bf16 Ps[64 * ALD];
  const int tid = threadIdx.x;
  const int wave = tid >> 6, lane = tid & 63;
  const int l16 = lane & 15, l4 = lane >> 4;
  const int qt = blockIdx.x, h = blockIdx.y, b = blockIdx.z;
  const int q0 = qt * 64;
  const long qoff = (long)b * 2048 * 1024 + h * 64;
  const int qrow_lane = q0 + wave * 16 + l4 * 4;  // + r
  const float scale = 0.125f;  // 1/sqrt(64)

  // stage Q (self)
#pragma unroll
  for (int i = 0; i < 2; i++) {
    int idx = tid + i * 256;
    int row = idx >> 3, ch = (idx & 7) * 8;
    *(bf16x8*)&Qs[row * ALD + ch] = *(const bf16x8*)(Qb + qoff + (long)(q0 + row) * 1024 + ch);
  }

  float o_self[4][4];
  float m_i[4], l_i[4];
  floatx4 oacc[4];

  for (int phase = 0; phase < 2; phase++) {
    const bf16* Kp;
    const bf16* Vp;
    long kvoff;
    int nkt;
    if (phase == 0) { Kp = Kb;  Vp = Vb;  kvoff = qoff;                          nkt = qt + 1; }
    else            { Kp = Kcb; Vp = Vcb; kvoff = (long)b * 512 * 1024 + h * 64; nkt = 8; }

    if (phase == 1) {
      __syncthreads();  // everyone done reading self-Q
#pragma unroll
      for (int i = 0; i < 2; i++) {
        int idx = tid + i * 256;
        int row = idx >> 3, ch = (idx & 7) * 8;
        *(bf16x8*)&Qs[row * ALD + ch] = *(const bf16x8*)(Qcb + qoff + (long)(q0 + row) * 1024 + ch);
      }
    }
#pragma unroll
    for (int r = 0; r < 4; r++) { m_i[r] = -__builtin_inff(); l_i[r] = 0.f; }
#pragma unroll
    for (int nt = 0; nt < 4; nt++) oacc[nt] = (floatx4){0.f, 0.f, 0.f, 0.f};

    for (int kt = 0; kt < nkt; kt++) {
      const int k0 = kt * 64;
      bf16x8 kreg[2], vreg[2];
#pragma unroll
      for (int i = 0; i < 2; i++) {
        int idx = tid + i * 256;
        int row = idx >> 3, ch = (idx & 7) * 8;
        kreg[i] = *(const bf16x8*)(Kp + kvoff + (long)(k0 + row) * 1024 + ch);
        int key = idx & 63, d0 = (idx >> 6) * 8;
        vreg[i] = *(const bf16x8*)(Vp + kvoff + (long)(k0 + key) * 1024 + d0);
      }
      __syncthreads();  // prior iteration's LDS reads done
#pragma unroll
      for (int i = 0; i < 2; i++) {
        int idx = tid + i * 256;
        int row = idx >> 3, ch = (idx & 7) * 8;
        *(bf16x8*)&Ks[row * ALD + ch] = kreg[i];
        int key = idx & 63, d0 = (idx >> 6) * 8;
#pragma unroll
        for (int j = 0; j < 8; j++) Vts[(d0 + j) * ALD + key] = vreg[i][j];
      }
      __syncthreads();

      // S = Q K^T (4 n-tiles x 2 k-steps)
      floatx4 sacc[4];
#pragma unroll
      for (int nt = 0; nt < 4; nt++) sacc[nt] = (floatx4){0.f, 0.f, 0.f, 0.f};
#pragma unroll
      for (int ds = 0; ds < 2; ds++) {
        bf16x8 af = *(const bf16x8*)&Qs[(wave * 16 + l16) * ALD + ds * 32 + l4 * 8];
#pragma unroll
        for (int nt = 0; nt < 4; nt++) {
          bf16x8 bfr = *(const bf16x8*)&Ks[(nt * 16 + l16) * ALD + ds * 32 + l4 * 8];
          sacc[nt] = __builtin_amdgcn_mfma_f32_16x16x32_bf16(af, bfr, sacc[nt], 0, 0, 0);
        }
      }
      // scale + causal mask + row max
      float rowmax[4];
#pragma unroll
      for (int r = 0; r < 4; r++) rowmax[r] = -__builtin_inff();
#pragma unroll
      for (int nt = 0; nt < 4; nt++) {
#pragma unroll
        for (int r = 0; r < 4; r++) {
          float s = sacc[nt][r] * scale;
          if (phase == 0 && (k0 + nt * 16 + l16 > qrow_lane + r)) s = -__builtin_inff();
          sacc[nt][r] = s;
          rowmax[r] = fmaxf(rowmax[r], s);
        }
      }
#pragma unroll
      for (int r = 0; r < 4; r++) {
#pragma unroll
        for (int off = 1; off < 16; off <<= 1)
          rowmax[r] = fmaxf(rowmax[r], __shfl_xor(rowmax[r], off));
      }
      float mn[4], alpha[4], rowsum[4];
#pragma unroll
      for (int r = 0; r < 4; r++) {
        mn[r] = fmaxf(m_i[r], rowmax[r]);
        alpha[r] = __expf(m_i[r] - mn[r]);  // first iter: exp(-inf)=0
        m_i[r] = mn[r];
        rowsum[r] = 0.f;
      }
#pragma unroll
      for (int nt = 0; nt < 4; nt++) {
#pragma unroll
        for (int r = 0; r < 4; r++) {
          float p = __expf(sacc[nt][r] - mn[r]);  // masked -> 0
          rowsum[r] += p;
          Ps[(wave * 16 + l4 * 4 + r) * ALD + nt * 16 + l16] = (bf16)p;  // C-layout -> LDS
        }
      }
#pragma unroll
      for (int r = 0; r < 4; r++) {
#pragma unroll
        for (int off = 1; off < 16; off <<= 1) rowsum[r] += __shfl_xor(rowsum[r], off);
        l_i[r] = l_i[r] * alpha[r] + rowsum[r];
      }
#pragma unroll
      for (int nt = 0; nt < 4; nt++) {
#pragma unroll
        for (int r = 0; r < 4; r++) oacc[nt][r] *= alpha[r];
      }
      // O += P V  (P read back in A-layout; within-wave rows only, no barrier needed)
#pragma unroll
      for (int ks = 0; ks < 2; ks++) {
        bf16x8 af = *(const bf16x8*)&Ps[(wave * 16 + l16) * ALD + ks * 32 + l4 * 8];
#pragma unroll
        for (int nt = 0; nt < 4; nt++) {
          bf16x8 bfr = *(const bf16x8*)&Vts[(nt * 16 + l16) * ALD + ks * 32 + l4 * 8];
          oacc[nt] = __builtin_amdgcn_mfma_f32_16x16x32_bf16(af, bfr, oacc[nt], 0, 0, 0);
        }
      }
    }  // kt

    if (phase == 0) {
#pragma unroll
      for (int nt = 0; nt < 4; nt++)
#pragma unroll
        for (int r = 0; r < 4; r++) o_self[nt][r] = oacc[nt][r] / l_i[r];
    } else {
#pragma unroll
      for (int nt = 0; nt < 4; nt++) {
        int col = h * 64 + nt * 16 + l16;
#pragma unroll
        for (int r = 0; r < 4; r++) {
          long row = (long)b * 2048 + q0 + wave * 16 + l4 * 4 + r;
          float y = o_self[nt][r] + oacc[nt][r] / l_i[r];
          Y[row * 1024 + col] = (bf16)y;
        }
      }
    }
  }  // phase
}

extern "C" void kernel_launch(void* const* d_in, const int* in_sizes, int n_in,
                              void* d_out, int out_size, void* d_ws, size_t ws_size,
                              hipStream_t stream) {
  const float* x   = (const float*)d_in[0];
  const float* xc  = (const float*)d_in[1];
  const float* Wk  = (const float*)d_in[2];  const float* bk  = (const float*)d_in[3];
  const float* Wq  = (const float*)d_in[4];  const float* bq  = (const float*)d_in[5];
  const float* Wv  = (const float*)d_in[6];  const float* bv  = (const float*)d_in[7];
  const float* Wck = (const float*)d_in[8];  const float* bck = (const float*)d_in[9];
  const float* Wcq = (const float*)d_in[10]; const float* bcq = (const float*)d_in[11];
  const float* Wcv = (const float*)d_in[12]; const float* bcv = (const float*)d_in[13];
  const float* Wp  = (const float*)d_in[14]; const float* bp  = (const float*)d_in[15];

  char* ws = (char*)d_ws;
  const size_t MB = 1ull << 20;
  bf16* WqT  = (bf16*)(ws + 0 * MB);   // [1024,1024] bf16
  bf16* WkT  = (bf16*)(ws + 2 * MB);
  bf16* WvT  = (bf16*)(ws + 4 * MB);
  bf16* WcqT = (bf16*)(ws + 6 * MB);
  bf16* WckT = (bf16*)(ws + 8 * MB);   // [1024,512]
  bf16* WcvT = (bf16*)(ws + 9 * MB);
  bf16* WpT  = (bf16*)(ws + 10 * MB);
  bf16* Qb   = (bf16*)(ws + 12 * MB);  // [4096,1024] bf16
  bf16* Kb2  = (bf16*)(ws + 20 * MB);
  bf16* Vb2  = (bf16*)(ws + 28 * MB);
  bf16* Qcb  = (bf16*)(ws + 36 * MB);
  bf16* Kcb  = (bf16*)(ws + 44 * MB);  // [1024,1024]
  bf16* Vcb  = (bf16*)(ws + 46 * MB);
  bf16* Yb   = (bf16*)(ws + 48 * MB);  // [4096,1024]

  dim3 tb(32, 8);
  wtrans_kernel<<<dim3(32, 32), tb, 0, stream>>>(Wq, WqT, 1024, 1024);
  wtrans_kernel<<<dim3(32, 32), tb, 0, stream>>>(Wk, WkT, 1024, 1024);
  wtrans_kernel<<<dim3(32, 32), tb, 0, stream>>>(Wv, WvT, 1024, 1024);
  wtrans_kernel<<<dim3(32, 32), tb, 0, stream>>>(Wcq, WcqT, 1024, 1024);
  wtrans_kernel<<<dim3(32, 16), tb, 0, stream>>>(Wck, WckT, 512, 1024);
  wtrans_kernel<<<dim3(32, 16), tb, 0, stream>>>(Wcv, WcvT, 512, 1024);
  wtrans_kernel<<<dim3(32, 32), tb, 0, stream>>>(Wp, WpT, 1024, 1024);

  gemm_bias_kernel<float, bf16><<<dim3(16, 64), 256, 0, stream>>>(x, WqT, bq, Qb, 4096, 1024, 1024);
  gemm_bias_kernel<float, bf16><<<dim3(16, 64), 256, 0, stream>>>(x, WkT, bk, Kb2, 4096, 1024, 1024);
  gemm_bias_kernel<float, bf16><<<dim3(16, 64), 256, 0, stream>>>(x, WvT, bv, Vb2, 4096, 1024, 1024);
  gemm_bias_kernel<float, bf16><<<dim3(16, 64), 256, 0, stream>>>(x, WcqT, bcq, Qcb, 4096, 1024, 1024);
  gemm_bias_kernel<float, bf16><<<dim3(16, 16), 256, 0, stream>>>(xc, WckT, bck, Kcb, 1024, 1024, 512);
  gemm_bias_kernel<float, bf16><<<dim3(16, 16), 256, 0, stream>>>(xc, WcvT, bcv, Vcb, 1024, 1024, 512);

  attn_kernel<<<dim3(32, 16, 2), 256, 0, stream>>>(Qb, Kb2, Vb2, Qcb, Kcb, Vcb, Yb);

  gemm_bias_kernel<bf16, float><<<dim3(16, 64), 256, 0, stream>>>(Yb, WpT, bp, (float*)d_out, 4096, 1024, 1024);
}

// Round 3
// 292.894 us; speedup vs baseline: 1.4653x; 1.4653x over previous
//
#include <hip/hip_runtime.h>
#include <hip/hip_bf16.h>
#include <type_traits>

typedef __bf16 bf16;
typedef __bf16 bf16x8 __attribute__((ext_vector_type(8)));
typedef float floatx4 __attribute__((ext_vector_type(4)));

#define QLD 72    // 64 + 8 pad (stride 144 B => +4 banks/row, 2-way free)
#define KLD 136   // 128 + 8 pad (stride 272 B => +4 banks/row)

__device__ __forceinline__ void glds16(const bf16* g, bf16* l) {
  __builtin_amdgcn_global_load_lds((const __attribute__((address_space(1))) void*)g,
                                   (__attribute__((address_space(3))) void*)l, 16, 0, 0);
}

// ---------------- fp32 -> bf16 convert ----------------
__global__ __launch_bounds__(256) void tobf16_kernel(const float* __restrict__ in,
                                                     bf16* __restrict__ out, int n4) {
  int i = blockIdx.x * 256 + threadIdx.x;
  if (i < n4) {
    float4 f = ((const float4*)in)[i];
    bf16 t[4] = {(bf16)f.x, (bf16)f.y, (bf16)f.z, (bf16)f.w};
    *(uint2*)&out[(long)i * 4] = *(const uint2*)t;
  }
}

// ---------------- concat up to 4 bias vectors of 1024 fp32 ----------------
__global__ __launch_bounds__(256) void concat4_kernel(float* __restrict__ dst,
                                                      const float* __restrict__ a,
                                                      const float* __restrict__ b,
                                                      const float* __restrict__ c,
                                                      const float* __restrict__ d) {
  int i = blockIdx.x * 256 + threadIdx.x;
  const float* s[4] = {a, b, c, d};
  dst[i] = s[i >> 10][i & 1023];
}

// ---------------- weight transpose + fp32->bf16: in [R,C] fp32 -> out [C,R] bf16 ----
__global__ __launch_bounds__(256) void wtrans_kernel(const float* __restrict__ in,
                                                     bf16* __restrict__ out,
                                                     int R, int C) {
  __shared__ bf16 t[32][33];
  int tx = threadIdx.x, ty = threadIdx.y;  // (32, 8)
  int c = blockIdx.x * 32 + tx;
#pragma unroll
  for (int i = 0; i < 4; i++) {
    int r = blockIdx.y * 32 + ty + i * 8;
    t[ty + i * 8][tx] = (bf16)in[(long)r * C + c];
  }
  __syncthreads();
  int oc = blockIdx.y * 32 + tx;
#pragma unroll
  for (int i = 0; i < 4; i++) {
    int orr = blockIdx.x * 32 + ty + i * 8;
    out[(long)orr * R + oc] = t[tx][ty + i * 8];
  }
}

// ---------------- 128x128 m97-style GEMM: C[M,N] = A[M,K] @ Bt[N,K]^T + bias -------
// Columns in [vcol0,vcol1) are written TRANSPOSED to Vt[b][h][d][t] (Lt tokens/batch).
// Columns >= vcol1 are compacted left by (vcol1-vcol0) in C.
template <typename OutT>
__global__ __launch_bounds__(256, 3) void gemm128(const bf16* __restrict__ A,
                                                  const bf16* __restrict__ Bt,
                                                  const float* __restrict__ bias,
                                                  OutT* __restrict__ C,
                                                  int M, int N, int K, int ldc,
                                                  bf16* __restrict__ Vt,
                                                  int vcol0, int vcol1, int Lt, int tok_shift) {
  __shared__ alignas(16) bf16 As[128 * 32];  // unpadded: global_load_lds needs lane-contig
  __shared__ alignas(16) bf16 Bs[128 * 32];
  const int tid = threadIdx.x, wave = tid >> 6, lane = tid & 63;
  const int l16 = lane & 15, l4 = lane >> 4;
  const int wm = wave & 1, wn = wave >> 1;
  const int n0 = blockIdx.x * 128, m0 = blockIdx.y * 128;
  const int lrow = lane >> 2, lch = (lane & 3) * 8;  // 16 rows x 4 chunks of 16B per inst

  floatx4 acc[4][4];
#pragma unroll
  for (int mt = 0; mt < 4; mt++)
#pragma unroll
    for (int nt = 0; nt < 4; nt++) acc[mt][nt] = (floatx4){0.f, 0.f, 0.f, 0.f};

  const bf16* Ag = A + (long)(m0 + wave * 32 + lrow) * K + lch;
  const bf16* Bg = Bt + (long)(n0 + wave * 32 + lrow) * K + lch;
  bf16* Al = &As[(wave * 32) * 32];  // wave-uniform LDS base; HW adds lane*16B
  bf16* Bl = &Bs[(wave * 32) * 32];

  for (int k0 = 0; k0 < K; k0 += 32) {
    __syncthreads();  // prior-iter LDS reads done
    glds16(Ag + k0, Al);
    glds16(Ag + k0 + (long)16 * K, Al + 16 * 32);
    glds16(Bg + k0, Bl);
    glds16(Bg + k0 + (long)16 * K, Bl + 16 * 32);
    __syncthreads();  // drains vmcnt: tiles resident
    bf16x8 a[4], b[4];
#pragma unroll
    for (int mt = 0; mt < 4; mt++) a[mt] = *(const bf16x8*)&As[(wm * 64 + mt * 16 + l16) * 32 + l4 * 8];
#pragma unroll
    for (int nt = 0; nt < 4; nt++) b[nt] = *(const bf16x8*)&Bs[(wn * 64 + nt * 16 + l16) * 32 + l4 * 8];
#pragma unroll
    for (int mt = 0; mt < 4; mt++)
#pragma unroll
      for (int nt = 0; nt < 4; nt++)
        acc[mt][nt] = __builtin_amdgcn_mfma_f32_16x16x32_bf16(a[mt], b[nt], acc[mt][nt], 0, 0, 0);
  }

  const bool vpath = (vcol0 >= 0) && (n0 >= vcol0) && (n0 < vcol1);
  if (!vpath) {
    const int coladj = (vcol0 >= 0 && n0 >= vcol1) ? (vcol1 - vcol0) : 0;
#pragma unroll
    for (int nt = 0; nt < 4; nt++) {
      int col = n0 + wn * 64 + nt * 16 + l16;
      float bv = bias[col];
#pragma unroll
      for (int mt = 0; mt < 4; mt++)
#pragma unroll
        for (int r = 0; r < 4; r++) {
          int row = m0 + wm * 64 + mt * 16 + l4 * 4 + r;
          float v = acc[mt][nt][r] + bv;
          if constexpr (std::is_same_v<OutT, float>) C[(long)row * ldc + col - coladj] = v;
          else                                       C[(long)row * ldc + col - coladj] = (bf16)v;
        }
    }
  } else {
#pragma unroll
    for (int nt = 0; nt < 4; nt++) {
      int col = n0 + wn * 64 + nt * 16 + l16;
      int c = col - vcol0, hh = c >> 6, dd = c & 63;
      float bv = bias[col];
#pragma unroll
      for (int mt = 0; mt < 4; mt++) {
        int t0 = m0 + wm * 64 + mt * 16 + l4 * 4;
        int bb = t0 >> tok_shift, t = t0 & ((1 << tok_shift) - 1);
        bf16 tmp[4];
#pragma unroll
        for (int r = 0; r < 4; r++) tmp[r] = (bf16)(acc[mt][nt][r] + bv);
        *(uint2*)&Vt[(((long)bb * 16 + hh) * 64 + dd) * Lt + t] = *(const uint2*)tmp;
      }
    }
  }
}

// ---------------- fused self(causal)+cross flash attention -------------------------
// grid (16, H, B): block handles q-tiles {x, 31-x} sequentially (uniform 25 k-iters).
// 128-key tiles; K/Vt register-prefetch; V arrives pre-transposed [b,h,d,t].
__global__ __launch_bounds__(256, 2) void attn_kernel(const bf16* __restrict__ QKQc,
                                                      const bf16* __restrict__ VtB,
                                                      const bf16* __restrict__ KcB,
                                                      const bf16* __restrict__ VctB,
                                                      bf16* __restrict__ Y) {
  __shared__ alignas(16) bf16 Qs[64 * QLD];
  __shared__ alignas(16) bf16 Ks[128 * QLD];
  __shared__ alignas(16) bf16 Vts[64 * KLD];   // [d][key]
  __shared__ alignas(16) bf16 Ps[64 * KLD];    // [q][key]
  const int tid = threadIdx.x, wave = tid >> 6, lane = tid & 63;
  const int l16 = lane & 15, l4 = lane >> 4;
  const int h = blockIdx.y, b = blockIdx.z;

  float o_self[4][4];
  float m_i[4], l_i[4];
  floatx4 oacc[4];

  for (int jj = 0; jj < 2; jj++) {
    const int qt = jj ? (31 - (int)blockIdx.x) : (int)blockIdx.x;
    const int q0 = qt * 64;
    const int qrow0 = q0 + wave * 16 + l4 * 4;

    for (int phase = 0; phase < 2; phase++) {
      const bf16* Qb;
      const bf16* Kb;
      const bf16* Vtb;
      int kstr, vtstr, nkt;
      if (phase == 0) {
        Qb = QKQc + (long)b * 2048 * 3072 + h * 64;
        Kb = Qb + 1024;                      kstr = 3072;
        Vtb = VtB + ((long)b * 16 + h) * 64 * 2048;  vtstr = 2048;
        nkt = (qt + 2) >> 1;
      } else {
        Qb = QKQc + (long)b * 2048 * 3072 + h * 64 + 2048;
        Kb = KcB + (long)b * 512 * 1024 + h * 64;    kstr = 1024;
        Vtb = VctB + ((long)b * 16 + h) * 64 * 512;  vtstr = 512;
        nkt = 4;
      }

      __syncthreads();  // all prior LDS reads done before restaging Q
      // stage Q * 0.125 (exact pow2 scale folded in)
#pragma unroll
      for (int i = 0; i < 2; i++) {
        int idx = tid + i * 256, row = idx >> 3, ch = (idx & 7) * 8;
        bf16x8 qv = *(const bf16x8*)(Qb + (long)(q0 + row) * 3072 + ch);
#pragma unroll
        for (int j = 0; j < 8; j++) qv[j] = (bf16)((float)qv[j] * 0.125f);
        *(bf16x8*)&Qs[row * QLD + ch] = qv;
      }
#pragma unroll
      for (int r = 0; r < 4; r++) { m_i[r] = -__builtin_inff(); l_i[r] = 0.f; }
#pragma unroll
      for (int nt = 0; nt < 4; nt++) oacc[nt] = (floatx4){0.f, 0.f, 0.f, 0.f};

      // prefetch tile 0
      bf16x8 kreg[4], vreg[4];
#pragma unroll
      for (int c = 0; c < 4; c++) {
        int idx = tid + c * 256;
        kreg[c] = *(const bf16x8*)(Kb + (long)(idx >> 3) * kstr + (idx & 7) * 8);
        vreg[c] = *(const bf16x8*)(Vtb + (long)(idx >> 4) * vtstr + (idx & 15) * 8);
      }

      for (int kt = 0; kt < nkt; kt++) {
        const int k0 = kt * 128;
        __syncthreads();  // prev-iter LDS reads done (also publishes Qs on kt=0)
#pragma unroll
        for (int c = 0; c < 4; c++) {
          int idx = tid + c * 256;
          *(bf16x8*)&Ks[(idx >> 3) * QLD + (idx & 7) * 8] = kreg[c];
          *(bf16x8*)&Vts[(idx >> 4) * KLD + (idx & 15) * 8] = vreg[c];
        }
        __syncthreads();
        if (kt + 1 < nkt) {  // prefetch next tile; vmcnt waited only at next store
          const int kn = k0 + 128;
#pragma unroll
          for (int c = 0; c < 4; c++) {
            int idx = tid + c * 256;
            kreg[c] = *(const bf16x8*)(Kb + (long)(kn + (idx >> 3)) * kstr + (idx & 7) * 8);
            vreg[c] = *(const bf16x8*)(Vtb + (long)(idx >> 4) * vtstr + kn + (idx & 15) * 8);
          }
        }

        // S = (Q*0.125) K^T : 64q x 128k
        floatx4 sacc[8];
#pragma unroll
        for (int nt = 0; nt < 8; nt++) sacc[nt] = (floatx4){0.f, 0.f, 0.f, 0.f};
#pragma unroll
        for (int ds = 0; ds < 2; ds++) {
          bf16x8 af = *(const bf16x8*)&Qs[(wave * 16 + l16) * QLD + ds * 32 + l4 * 8];
#pragma unroll
          for (int nt = 0; nt < 8; nt++) {
            bf16x8 bfr = *(const bf16x8*)&Ks[(nt * 16 + l16) * QLD + ds * 32 + l4 * 8];
            sacc[nt] = __builtin_amdgcn_mfma_f32_16x16x32_bf16(af, bfr, sacc[nt], 0, 0, 0);
          }
        }
        // causal mask: only the last self tile straddles the diagonal
        if (phase == 0 && kt == nkt - 1) {
          int keyb = k0 + l16;
#pragma unroll
          for (int nt = 0; nt < 8; nt++) {
            int key = keyb + nt * 16;
#pragma unroll
            for (int r = 0; r < 4; r++)
              if (key > qrow0 + r) sacc[nt][r] = -__builtin_inff();
          }
        }
        // online softmax
        float mx[4];
#pragma unroll
        for (int r = 0; r < 4; r++) mx[r] = m_i[r];
#pragma unroll
        for (int nt = 0; nt < 8; nt++)
#pragma unroll
          for (int r = 0; r < 4; r++) mx[r] = fmaxf(mx[r], sacc[nt][r]);
#pragma unroll
        for (int r = 0; r < 4; r++) {
#pragma unroll
          for (int off = 1; off < 16; off <<= 1) mx[r] = fmaxf(mx[r], __shfl_xor(mx[r], off));
        }
        float alpha[4], rs[4];
#pragma unroll
        for (int r = 0; r < 4; r++) {
          alpha[r] = __expf(m_i[r] - mx[r]);
          m_i[r] = mx[r];
          rs[r] = 0.f;
        }
#pragma unroll
        for (int nt = 0; nt < 8; nt++)
#pragma unroll
          for (int r = 0; r < 4; r++) {
            float p = __expf(sacc[nt][r] - mx[r]);
            rs[r] += p;
            Ps[(wave * 16 + l4 * 4 + r) * KLD + nt * 16 + l16] = (bf16)p;
          }
#pragma unroll
        for (int r = 0; r < 4; r++) {
#pragma unroll
          for (int off = 1; off < 16; off <<= 1) rs[r] += __shfl_xor(rs[r], off);
          l_i[r] = l_i[r] * alpha[r] + rs[r];
        }
#pragma unroll
        for (int nt = 0; nt < 4; nt++)
#pragma unroll
          for (int r = 0; r < 4; r++) oacc[nt][r] *= alpha[r];
        // O += P V  (wave-private P rows; lgkmcnt ordering, no barrier)
#pragma unroll
        for (int ks = 0; ks < 4; ks++) {
          bf16x8 af = *(const bf16x8*)&Ps[(wave * 16 + l16) * KLD + ks * 32 + l4 * 8];
#pragma unroll
          for (int nt = 0; nt < 4; nt++) {
            bf16x8 bfr = *(const bf16x8*)&Vts[(nt * 16 + l16) * KLD + ks * 32 + l4 * 8];
            oacc[nt] = __builtin_amdgcn_mfma_f32_16x16x32_bf16(af, bfr, oacc[nt], 0, 0, 0);
          }
        }
      }  // kt

      if (phase == 0) {
#pragma unroll
        for (int r = 0; r < 4; r++) {
          float inv = 1.0f / l_i[r];
#pragma unroll
          for (int nt = 0; nt < 4; nt++) o_self[nt][r] = oacc[nt][r] * inv;
        }
      } else {
#pragma unroll
        for (int r = 0; r < 4; r++) {
          float inv = 1.0f / l_i[r];
          long row = (long)b * 2048 + q0 + wave * 16 + l4 * 4 + r;
#pragma unroll
          for (int nt = 0; nt < 4; nt++) {
            int col = h * 64 + nt * 16 + l16;
            Y[row * 1024 + col] = (bf16)(o_self[nt][r] + oacc[nt][r] * inv);
          }
        }
      }
    }  // phase
  }  // jj
}

extern "C" void kernel_launch(void* const* d_in, const int* in_sizes, int n_in,
                              void* d_out, int out_size, void* d_ws, size_t ws_size,
                              hipStream_t stream) {
  const float* x   = (const float*)d_in[0];
  const float* xc  = (const float*)d_in[1];
  const float* Wk  = (const float*)d_in[2];  const float* bk  = (const float*)d_in[3];
  const float* Wq  = (const float*)d_in[4];  const float* bq  = (const float*)d_in[5];
  const float* Wv  = (const float*)d_in[6];  const float* bv  = (const float*)d_in[7];
  const float* Wck = (const float*)d_in[8];  const float* bck = (const float*)d_in[9];
  const float* Wcq = (const float*)d_in[10]; const float* bcq = (const float*)d_in[11];
  const float* Wcv = (const float*)d_in[12]; const float* bcv = (const float*)d_in[13];
  const float* Wp  = (const float*)d_in[14]; const float* bp  = (const float*)d_in[15];

  char* ws = (char*)d_ws;
  const size_t MB = 1ull << 20;
  bf16*  WT_all = (bf16*)(ws + 0);         // [4096][1024]: Q|K|V|Qc
  bf16*  WC_all = (bf16*)(ws + 8 * MB);    // [2048][512]: Kc|Vc
  bf16*  WpT    = (bf16*)(ws + 10 * MB);   // [1024][1024]
  bf16*  xbf    = (bf16*)(ws + 12 * MB);   // [4096][1024]; Yb overlays after projections
  bf16*  Yb     = xbf;
  bf16*  xcbf   = (bf16*)(ws + 20 * MB);   // [1024][512]
  float* bias4  = (float*)(ws + 21 * MB);          // [4096]: bq|bk|bv|bcq
  float* biasc  = (float*)(ws + 21 * MB + 65536);  // [2048]: bck|bcv
  bf16*  QKQc   = (bf16*)(ws + 22 * MB);   // [4096][3072]: Q|K|Qc (compacted)
  bf16*  VtB    = (bf16*)(ws + 46 * MB);   // [2][16][64][2048]
  bf16*  KcB    = (bf16*)(ws + 54 * MB);   // [1024][1024]
  bf16*  VctB   = (bf16*)(ws + 56 * MB);   // [2][16][64][512]

  tobf16_kernel<<<4096, 256, 0, stream>>>(x, xbf, 1048576);
  tobf16_kernel<<<512, 256, 0, stream>>>(xc, xcbf, 131072);

  dim3 tb(32, 8);
  wtrans_kernel<<<dim3(32, 32), tb, 0, stream>>>(Wq,  WT_all + 0ll * 1024 * 1024, 1024, 1024);
  wtrans_kernel<<<dim3(32, 32), tb, 0, stream>>>(Wk,  WT_all + 1ll * 1024 * 1024, 1024, 1024);
  wtrans_kernel<<<dim3(32, 32), tb, 0, stream>>>(Wv,  WT_all + 2ll * 1024 * 1024, 1024, 1024);
  wtrans_kernel<<<dim3(32, 32), tb, 0, stream>>>(Wcq, WT_all + 3ll * 1024 * 1024, 1024, 1024);
  wtrans_kernel<<<dim3(32, 16), tb, 0, stream>>>(Wck, WC_all + 0ll * 1024 * 512, 512, 1024);
  wtrans_kernel<<<dim3(32, 16), tb, 0, stream>>>(Wcv, WC_all + 1ll * 1024 * 512, 512, 1024);
  wtrans_kernel<<<dim3(32, 32), tb, 0, stream>>>(Wp,  WpT, 1024, 1024);

  concat4_kernel<<<16, 256, 0, stream>>>(bias4, bq, bk, bv, bcq);
  concat4_kernel<<<8, 256, 0, stream>>>(biasc, bck, bcv, bck, bcv);

  // fused QKV+Qc projection: N=4096; V section [2048,3072) -> VtB transposed
  gemm128<bf16><<<dim3(32, 32), 256, 0, stream>>>(xbf, WT_all, bias4, QKQc,
                                                  4096, 4096, 1024, 3072,
                                                  VtB, 2048, 3072, 2048, 11);
  // fused cross K+V: N=2048; Vc section [1024,2048) -> VctB transposed
  gemm128<bf16><<<dim3(16, 8), 256, 0, stream>>>(xcbf, WC_all, biasc, KcB,
                                                 1024, 2048, 512, 1024,
                                                 VctB, 1024, 2048, 512, 9);

  attn_kernel<<<dim3(16, 16, 2), 256, 0, stream>>>(QKQc, VtB, KcB, VctB, Yb);

  gemm128<float><<<dim3(8, 32), 256, 0, stream>>>(Yb, WpT, bp, (float*)d_out,
                                                  4096, 1024, 1024, 1024,
                                                  nullptr, -1, -1, 0, 0);
}